// Round 2
// baseline (409.945 us; speedup 1.0000x reference)
//
#include <hip/hip_runtime.h>
#include <hip/hip_bf16.h>
#include <cstdint>

#define BB 8
#define CC 16
#define DD 32
#define HH 112
#define WW 112
#define TT 16        // D_OUT
#define HID 256
#define OUTN 128
#define INSZ 784     // C*7*7
#define NCACHE 48    // whhP rows pinned in LDS (48*768*4 = 144 KB; +4 KB state <= 160 KB/CU)

__device__ __forceinline__ float bf16lo(uint32_t u) { return __uint_as_float(u << 16); }
__device__ __forceinline__ float bf16hi(uint32_t u) { return __uint_as_float(u & 0xffff0000u); }
__device__ __forceinline__ float bf16s(uint16_t u)  { return __uint_as_float(((uint32_t)u) << 16); }

__device__ __forceinline__ uint16_t f32_to_bf16_rne(float f) {
    uint32_t u = __float_as_uint(f);
    return (uint16_t)((u + 0x7fffu + ((u >> 16) & 1u)) >> 16);
}

// ---------------------------------------------------------------------------
// prep: detect (per-block, deterministic) + pool + W_ih transpose + W_hh pack
//       + gi bias init, all in ONE launch.
// blocks [0,2048): pool (long pole, scheduled first)
// blocks [2048,4400): wihT transpose (2352)
// blocks [4400,4784): whhP bf16 pack (384)
// blocks [4784,5168): gi = b_ih init (384)
// Every block self-detects dtype from x[0:8192] (same PROVEN >400 threshold);
// block 2048 publishes the flag for gru.
// ---------------------------------------------------------------------------
__global__ __launch_bounds__(256) void prep_kernel(const void* __restrict__ xv,
                                                   float* __restrict__ seq,
                                                   const void* __restrict__ Wih,
                                                   float* __restrict__ wihT,
                                                   const void* __restrict__ Whh,
                                                   uint32_t* __restrict__ whhP,
                                                   const void* __restrict__ bih,
                                                   float* __restrict__ gi,
                                                   int* __restrict__ flagp) {
    __shared__ float chunk[6272];
    __shared__ int cnt;
    const int tid = threadIdx.x;
    const int blk = blockIdx.x;

    // ---- per-block dtype detection (PROVEN semantics, L2-broadcast reads) ----
    if (tid == 0) cnt = 0;
    __syncthreads();
    {
        const uint16_t* xu = (const uint16_t*)xv;
        int local = 0;
        for (int i = tid; i < 8192; i += 256) {
            uint32_t e = (xu[i] >> 7) & 0xFFu;
            if (e == 0u || e >= 0x90u) local++;
        }
        atomicAdd(&cnt, local);
    }
    __syncthreads();
    const int isf32 = (cnt > 400) ? 1 : 0;
    if (blk == 2048 && tid == 0) *flagp = isf32;   // for gru (stream-ordered)

    if (blk < 2048) {
        // ---------------- pool: x -> seq (T,B,INSZ) f32, mean over 512 -------
        int t = blk & 15, c = (blk >> 4) & 15, b = blk >> 8;
        long base = (long)(((b * CC + c) * DD) + t * 2) * (HH * WW);
        float s = 0.0f;
        if (!isf32) {
            const uint4* p = reinterpret_cast<const uint4*>((const uint16_t*)xv + base);
            for (int m = tid; m < 3136; m += 256) {
                uint4 v = p[m];
                chunk[m] = bf16lo(v.x) + bf16hi(v.x) + bf16lo(v.y) + bf16hi(v.y)
                         + bf16lo(v.z) + bf16hi(v.z) + bf16lo(v.w) + bf16hi(v.w);
            }
            __syncthreads();
            if (tid < 49) {
                int h2 = tid / 7, w2 = tid - h2 * 7;
                #pragma unroll
                for (int d = 0; d < 2; d++)
                    for (int hh = 0; hh < 16; hh++) {
                        int row = d * 1568 + (h2 * 16 + hh) * 14 + w2 * 2;
                        s += chunk[row] + chunk[row + 1];
                    }
            }
        } else {
            const float4* p = reinterpret_cast<const float4*>((const float*)xv + base);
            for (int m = tid; m < 6272; m += 256) {
                float4 v = p[m];
                chunk[m] = v.x + v.y + v.z + v.w;
            }
            __syncthreads();
            if (tid < 49) {
                int h2 = tid / 7, w2 = tid - h2 * 7;
                #pragma unroll
                for (int d = 0; d < 2; d++)
                    for (int hh = 0; hh < 16; hh++) {
                        int row = d * 3136 + (h2 * 16 + hh) * 28 + w2 * 4;
                        s += chunk[row] + chunk[row + 1] + chunk[row + 2] + chunk[row + 3];
                    }
            }
        }
        if (tid < 49) {
            seq[(long)(t * BB + b) * INSZ + c * 49 + tid] = s * (1.0f / 512.0f);
        }
    } else if (blk < 4400) {
        // ---------------- W_ih -> f32 transposed wihT[k][768] ----------------
        int g = (blk - 2048) * 256 + tid;         // 602112 exactly = 768*784
        int j = g / INSZ, k = g - j * INSZ;
        float v = isf32 ? ((const float*)Wih)[g] : bf16s(((const uint16_t*)Wih)[g]);
        wihT[(long)k * 768 + j] = v;
    } else if (blk < 4784) {
        // ---------------- W_hh -> packed bf16 pairs whhP[kk][768] ------------
        int g = (blk - 4400) * 256 + tid;         // 98304 exactly = 768*128 pairs
        int jr = g >> 7, kk = g & 127;
        uint32_t u;
        if (isf32) {
            float2 v = ((const float2*)Whh)[g];   // W[j][2kk], W[j][2kk+1]
            u = (uint32_t)f32_to_bf16_rne(v.x) | ((uint32_t)f32_to_bf16_rne(v.y) << 16);
        } else {
            u = ((const uint32_t*)Whh)[g];
        }
        whhP[kk * 768 + jr] = u;
    } else {
        // ---------------- gi = b_ih (bias pre-init for atomicAdd) ------------
        int g = (blk - 4784) * 256 + tid;         // 98304 exactly = 128*768
        int jj = g % 768;
        float bv = isf32 ? ((const float*)bih)[jj] : bf16s(((const uint16_t*)bih)[jj]);
        gi[g] = bv;
    }
}

// ---------------------------------------------------------------------------
// gi (UNCHANGED from r1 PASS): 192 blocks = 3 j-groups x 32 tb-groups x 2 k-halves.
// Partials combined via f32 atomicAdd into bias-pre-initialized gi.
// ---------------------------------------------------------------------------
__global__ __launch_bounds__(256) void gi_kernel(const float* __restrict__ seq,
                                                 const float* __restrict__ wihT,
                                                 float* __restrict__ gi) {
    int jg = blockIdx.x % 3;
    int tbg = (blockIdx.x / 3) & 31;
    int kh = blockIdx.x / 96;                 // 0 or 1
    int tb0 = tbg * 4;
    int j = jg * 256 + threadIdx.x;
    int k0 = kh * 392;
    __shared__ __align__(16) float s_in[392 * 4];
    const float* sbase = seq + (long)tb0 * INSZ + k0;
    for (int idx = threadIdx.x; idx < 392 * 4; idx += 256) {
        int i = idx / 392, k = idx - i * 392;
        s_in[k * 4 + i] = sbase[(long)i * INSZ + k];
    }
    __syncthreads();
    float a0 = 0.0f, a1 = 0.0f, a2 = 0.0f, a3 = 0.0f;
    const float* wp = wihT + (long)k0 * 768 + j;
    const float4* s4 = reinterpret_cast<const float4*>(s_in);
    #pragma unroll 8
    for (int k = 0; k < 392; k++) {
        float w = wp[(long)k * 768];
        float4 sv = s4[k];
        a0 += w * sv.x; a1 += w * sv.y; a2 += w * sv.z; a3 += w * sv.w;
    }
    atomicAdd(&gi[(long)(tb0 + 0) * 768 + j], a0);
    atomicAdd(&gi[(long)(tb0 + 1) * 768 + j], a1);
    atomicAdd(&gi[(long)(tb0 + 2) * 768 + j], a2);
    atomicAdd(&gi[(long)(tb0 + 3) * 768 + j], a3);
}

// ---------------------------------------------------------------------------
// Sequential GRU (UNCHANGED from r1 PASS): rolled structure + NCACHE=48 rows
// pinned in LDS (144 KB). L2-tail loop issued first.
// ---------------------------------------------------------------------------
__global__ __launch_bounds__(768) void gru_kernel(const float* __restrict__ gi,
                                                  const uint32_t* __restrict__ whhP,
                                                  const void* __restrict__ bhh,
                                                  const void* __restrict__ Wout,
                                                  const void* __restrict__ bout,
                                                  void* __restrict__ out,
                                                  const int* __restrict__ flag) {
    const int isf32 = *flag;
    int b = blockIdx.x;
    int j = threadIdx.x;
    __shared__ __align__(16) float h_s[HID];
    __shared__ __align__(16) float g_s[768];
    __shared__ __align__(16) uint32_t w_s[NCACHE * 768];   // 144 KB
    if (j < HID) h_s[j] = 0.0f;
    float bh = isf32 ? ((const float*)bhh)[j] : bf16s(((const uint16_t*)bhh)[j]);
    for (int idx = j; idx < NCACHE * 768; idx += 768) w_s[idx] = whhP[idx];
    const uint32_t* wpg = whhP + (long)NCACHE * 768 + j;   // L2-resident tail rows
    const uint32_t* wls = w_s + j;
    __syncthreads();
    #pragma unroll 1
    for (int t = 0; t < TT; t++) {
        float a0 = bh, a1 = 0.0f;
        const float2* h2p = reinterpret_cast<const float2*>(h_s);
        #pragma unroll 8
        for (int kk = 0; kk < 128 - NCACHE; kk++) {
            uint32_t u = wpg[kk * 768];          // coalesced u32 stream from L2
            float2 hv = h2p[NCACHE + kk];        // LDS broadcast
            a0 += bf16lo(u) * hv.x;
            a1 += bf16hi(u) * hv.y;
        }
        #pragma unroll 8
        for (int kk = 0; kk < NCACHE; kk++) {
            uint32_t u = wls[kk * 768];          // LDS, 2-way (free) bank pattern
            float2 hv = h2p[kk];
            a0 += bf16lo(u) * hv.x;
            a1 += bf16hi(u) * hv.y;
        }
        g_s[j] = a0 + a1;
        __syncthreads();                         // g ready; dots done with h_s
        if (j < HID) {
            const float* gp = gi + (long)(t * BB + b) * 768;
            float r = 1.0f / (1.0f + __expf(-(gp[j]       + g_s[j])));
            float z = 1.0f / (1.0f + __expf(-(gp[j + 256] + g_s[j + 256])));
            float npre = gp[j + 512] + r * g_s[j + 512];
            float n = 2.0f / (1.0f + __expf(-2.0f * npre)) - 1.0f;  // tanh
            h_s[j] = (1.0f - z) * n + z * h_s[j];
        }
        __syncthreads();                         // h ready for next step
    }
    if (j < OUTN) {
        float acc = isf32 ? ((const float*)bout)[j] : bf16s(((const uint16_t*)bout)[j]);
        if (!isf32) {
            const uint4* wo = reinterpret_cast<const uint4*>((const uint16_t*)Wout + (long)j * HID);
            #pragma unroll
            for (int k = 0; k < 32; k++) {
                uint4 v = wo[k];
                const float* hp2 = &h_s[k * 8];
                acc += bf16lo(v.x) * hp2[0] + bf16hi(v.x) * hp2[1]
                     + bf16lo(v.y) * hp2[2] + bf16hi(v.y) * hp2[3]
                     + bf16lo(v.z) * hp2[4] + bf16hi(v.z) * hp2[5]
                     + bf16lo(v.w) * hp2[6] + bf16hi(v.w) * hp2[7];
            }
            ((uint16_t*)out)[b * OUTN + j] = f32_to_bf16_rne(acc);
        } else {
            const float4* wo = reinterpret_cast<const float4*>((const float*)Wout + (long)j * HID);
            #pragma unroll
            for (int k = 0; k < 64; k++) {
                float4 v = wo[k];
                const float* hp2 = &h_s[k * 4];
                acc += v.x * hp2[0] + v.y * hp2[1] + v.z * hp2[2] + v.w * hp2[3];
            }
            ((float*)out)[b * OUTN + j] = acc;
        }
    }
}

extern "C" void kernel_launch(void* const* d_in, const int* in_sizes, int n_in,
                              void* d_out, int out_size, void* d_ws, size_t ws_size,
                              hipStream_t stream) {
    const void* x    = d_in[0];  // 8*16*32*112*112
    const void* Wih  = d_in[1];  // 768*784
    const void* Whh  = d_in[2];  // 768*256
    const void* bih  = d_in[3];  // 768
    const void* bhh  = d_in[4];  // 768
    const void* Wout = d_in[5];  // 128*256
    const void* bout = d_in[6];  // 128

    char* ws = (char*)d_ws;
    float*    seq  = (float*)ws;                  // 401408 B
    float*    gi   = (float*)(ws + 401408);       // 393216 B
    float*    wihT = (float*)(ws + 1048576);      // 2408448 B  [784][768] f32
    uint32_t* whhP = (uint32_t*)(ws + 4194304);   // 393216 B   [128][768] u32
    int*     flagp = (int*)(ws + 8388608);

    prep_kernel<<<5168, 256, 0, stream>>>(x, seq, Wih, wihT, Whh, whhP, bih, gi, flagp);
    gi_kernel<<<192, 256, 0, stream>>>(seq, wihT, gi);
    gru_kernel<<<8, 768, 0, stream>>>(gi, whhP, bhh, Wout, bout, d_out, flagp);
}

// Round 4
// 405.883 us; speedup vs baseline: 1.0100x; 1.0100x over previous
//
#include <hip/hip_runtime.h>
#include <hip/hip_bf16.h>
#include <cstdint>

#define BB 8
#define CC 16
#define DD 32
#define HH 112
#define WW 112
#define TT 16        // D_OUT
#define HID 256
#define OUTN 128
#define INSZ 784     // C*7*7
#define NCACHE 48    // whhP rows pinned in LDS (48*768*4 = 144 KB; +4 KB state = 148 KB — PROVEN r1/r2)

__device__ __forceinline__ float bf16lo(uint32_t u) { return __uint_as_float(u << 16); }
__device__ __forceinline__ float bf16hi(uint32_t u) { return __uint_as_float(u & 0xffff0000u); }
__device__ __forceinline__ float bf16s(uint16_t u)  { return __uint_as_float(((uint32_t)u) << 16); }

__device__ __forceinline__ uint16_t f32_to_bf16_rne(float f) {
    uint32_t u = __float_as_uint(f);
    return (uint16_t)((u + 0x7fffu + ((u >> 16) & 1u)) >> 16);
}

// ---------------------------------------------------------------------------
// Dtype detector (PROVEN r1): flag=1 -> float32, 0 -> bfloat16.
// ---------------------------------------------------------------------------
__global__ __launch_bounds__(256) void detect_kernel(const uint16_t* __restrict__ x,
                                                     int* __restrict__ flag) {
    __shared__ int cnt;
    if (threadIdx.x == 0) cnt = 0;
    __syncthreads();
    int local = 0;
    for (int i = threadIdx.x; i < 8192; i += 256) {
        uint32_t e = (x[i] >> 7) & 0xFFu;
        if (e == 0u || e >= 0x90u) local++;
    }
    atomicAdd(&cnt, local);
    __syncthreads();
    if (threadIdx.x == 0) *flag = (cnt > 400) ? 1 : 0;
}

// ---------------------------------------------------------------------------
// Pool (r1 PROVEN standalone version): x -> seq (T,B,INSZ) f32, mean over 512.
// ---------------------------------------------------------------------------
__global__ __launch_bounds__(256) void pool_kernel(const void* __restrict__ xv,
                                                   float* __restrict__ seq,
                                                   const int* __restrict__ flag) {
    const int isf32 = *flag;
    int gid = blockIdx.x;                 // 2048 blocks
    int t = gid & 15, c = (gid >> 4) & 15, b = gid >> 8;
    long base = (long)(((b * CC + c) * DD) + t * 2) * (HH * WW);
    __shared__ float chunk[6272];
    int tid = threadIdx.x;
    float s = 0.0f;
    if (!isf32) {
        const uint4* p = reinterpret_cast<const uint4*>((const uint16_t*)xv + base);
        for (int m = tid; m < 3136; m += 256) {
            uint4 v = p[m];
            chunk[m] = bf16lo(v.x) + bf16hi(v.x) + bf16lo(v.y) + bf16hi(v.y)
                     + bf16lo(v.z) + bf16hi(v.z) + bf16lo(v.w) + bf16hi(v.w);
        }
        __syncthreads();
        if (tid < 49) {
            int h2 = tid / 7, w2 = tid - h2 * 7;
            #pragma unroll
            for (int d = 0; d < 2; d++)
                for (int hh = 0; hh < 16; hh++) {
                    int row = d * 1568 + (h2 * 16 + hh) * 14 + w2 * 2;
                    s += chunk[row] + chunk[row + 1];
                }
        }
    } else {
        const float4* p = reinterpret_cast<const float4*>((const float*)xv + base);
        for (int m = tid; m < 6272; m += 256) {
            float4 v = p[m];
            chunk[m] = v.x + v.y + v.z + v.w;
        }
        __syncthreads();
        if (tid < 49) {
            int h2 = tid / 7, w2 = tid - h2 * 7;
            #pragma unroll
            for (int d = 0; d < 2; d++)
                for (int hh = 0; hh < 16; hh++) {
                    int row = d * 3136 + (h2 * 16 + hh) * 28 + w2 * 4;
                    s += chunk[row] + chunk[row + 1] + chunk[row + 2] + chunk[row + 3];
                }
        }
    }
    if (tid < 49) {
        seq[(long)(t * BB + b) * INSZ + c * 49 + tid] = s * (1.0f / 512.0f);
    }
}

// ---------------------------------------------------------------------------
// pack_all v2: LDS-tiled COALESCED W_ih transpose (was: scattered 4B stores,
// 64 transactions/wave) + W_hh bf16-pack + gi bias init.
// blocks [0,156): wihT 64x64 tiled transpose (12 j-tiles x 13 k-tiles)
// blocks [156,540): whhP bf16 pack (384)
// blocks [540,924): gi = b_ih init (384)
// ---------------------------------------------------------------------------
__global__ __launch_bounds__(256) void pack_all(const void* __restrict__ Wih,
                                                float* __restrict__ wihT,
                                                const void* __restrict__ Whh,
                                                uint32_t* __restrict__ whhP,
                                                const void* __restrict__ bih,
                                                float* __restrict__ gi,
                                                const int* __restrict__ flag) {
    const int isf32 = *flag;
    const int blk = blockIdx.x;
    const int tid = threadIdx.x;
    __shared__ float tlds[64][65];            // +1 pad: conflict-free both phases
    if (blk < 156) {
        // ---- tiled transpose: Wih[768][784] -> wihT[784][768] --------------
        int jt = blk / 13, kt = blk - jt * 13;
        int j0 = jt * 64, k0 = kt * 64;
        int rr = tid >> 6, c = tid & 63;
        #pragma unroll
        for (int r0 = 0; r0 < 64; r0 += 4) {
            int jL = r0 + rr;
            int k = k0 + c;
            if (k < INSZ) {                   // coalesced 256B/wave read along k
                long idx = (long)(j0 + jL) * INSZ + k;
                tlds[jL][c] = isf32 ? ((const float*)Wih)[idx]
                                    : bf16s(((const uint16_t*)Wih)[idx]);
            }
        }
        __syncthreads();
        #pragma unroll
        for (int r0 = 0; r0 < 64; r0 += 4) {
            int kL = r0 + rr;
            int k = k0 + kL;
            if (k < INSZ) {                   // coalesced 256B/wave write along j
                wihT[(long)k * 768 + j0 + c] = tlds[c][kL];
            }
        }
    } else if (blk < 540) {
        // ---- W_hh -> packed bf16 pairs whhP[kk][768] -----------------------
        int g = (blk - 156) * 256 + tid;      // 98304 exactly = 768*128 pairs
        int jr = g >> 7, kk = g & 127;
        uint32_t u;
        if (isf32) {
            float2 v = ((const float2*)Whh)[g];   // W[j][2kk], W[j][2kk+1]
            u = (uint32_t)f32_to_bf16_rne(v.x) | ((uint32_t)f32_to_bf16_rne(v.y) << 16);
        } else {
            u = ((const uint32_t*)Whh)[g];
        }
        whhP[kk * 768 + jr] = u;
    } else {
        // ---- gi = b_ih (bias pre-init for gi_kernel's atomicAdd) -----------
        int g = (blk - 540) * 256 + tid;      // 98304 exactly = 128*768
        int jj = g % 768;
        float bv = isf32 ? ((const float*)bih)[jj] : bf16s(((const uint16_t*)bih)[jj]);
        gi[g] = bv;
    }
}

// ---------------------------------------------------------------------------
// gi (UNCHANGED from r1 PASS): 192 blocks = 3 j-groups x 32 tb-groups x 2 k-halves.
// Partials combined via f32 atomicAdd into bias-pre-initialized gi.
// ---------------------------------------------------------------------------
__global__ __launch_bounds__(256) void gi_kernel(const float* __restrict__ seq,
                                                 const float* __restrict__ wihT,
                                                 float* __restrict__ gi) {
    int jg = blockIdx.x % 3;
    int tbg = (blockIdx.x / 3) & 31;
    int kh = blockIdx.x / 96;                 // 0 or 1
    int tb0 = tbg * 4;
    int j = jg * 256 + threadIdx.x;
    int k0 = kh * 392;
    __shared__ __align__(16) float s_in[392 * 4];
    const float* sbase = seq + (long)tb0 * INSZ + k0;
    for (int idx = threadIdx.x; idx < 392 * 4; idx += 256) {
        int i = idx / 392, k = idx - i * 392;
        s_in[k * 4 + i] = sbase[(long)i * INSZ + k];
    }
    __syncthreads();
    float a0 = 0.0f, a1 = 0.0f, a2 = 0.0f, a3 = 0.0f;
    const float* wp = wihT + (long)k0 * 768 + j;
    const float4* s4 = reinterpret_cast<const float4*>(s_in);
    #pragma unroll 8
    for (int k = 0; k < 392; k++) {
        float w = wp[(long)k * 768];
        float4 sv = s4[k];
        a0 += w * sv.x; a1 += w * sv.y; a2 += w * sv.z; a3 += w * sv.w;
    }
    atomicAdd(&gi[(long)(tb0 + 0) * 768 + j], a0);
    atomicAdd(&gi[(long)(tb0 + 1) * 768 + j], a1);
    atomicAdd(&gi[(long)(tb0 + 2) * 768 + j], a2);
    atomicAdd(&gi[(long)(tb0 + 3) * 768 + j], a3);
}

// ---------------------------------------------------------------------------
// Sequential GRU (r1 PROVEN, byte-identical: NCACHE=48, 148 KB LDS).
// ---------------------------------------------------------------------------
__global__ __launch_bounds__(768) void gru_kernel(const float* __restrict__ gi,
                                                  const uint32_t* __restrict__ whhP,
                                                  const void* __restrict__ bhh,
                                                  const void* __restrict__ Wout,
                                                  const void* __restrict__ bout,
                                                  void* __restrict__ out,
                                                  const int* __restrict__ flag) {
    const int isf32 = *flag;
    int b = blockIdx.x;
    int j = threadIdx.x;
    __shared__ __align__(16) float h_s[HID];
    __shared__ __align__(16) float g_s[768];
    __shared__ __align__(16) uint32_t w_s[NCACHE * 768];   // 144 KB
    if (j < HID) h_s[j] = 0.0f;
    float bh = isf32 ? ((const float*)bhh)[j] : bf16s(((const uint16_t*)bhh)[j]);
    for (int idx = j; idx < NCACHE * 768; idx += 768) w_s[idx] = whhP[idx];
    const uint32_t* wpg = whhP + (long)NCACHE * 768 + j;   // L2-resident tail rows
    const uint32_t* wls = w_s + j;
    __syncthreads();
    #pragma unroll 1
    for (int t = 0; t < TT; t++) {
        float a0 = bh, a1 = 0.0f;
        const float2* h2p = reinterpret_cast<const float2*>(h_s);
        #pragma unroll 8
        for (int kk = 0; kk < 128 - NCACHE; kk++) {
            uint32_t u = wpg[kk * 768];          // coalesced u32 stream from L2
            float2 hv = h2p[NCACHE + kk];        // LDS broadcast
            a0 += bf16lo(u) * hv.x;
            a1 += bf16hi(u) * hv.y;
        }
        #pragma unroll 8
        for (int kk = 0; kk < NCACHE; kk++) {
            uint32_t u = wls[kk * 768];          // LDS, 2-way (free) bank pattern
            float2 hv = h2p[kk];
            a0 += bf16lo(u) * hv.x;
            a1 += bf16hi(u) * hv.y;
        }
        g_s[j] = a0 + a1;
        __syncthreads();                         // g ready; dots done with h_s
        if (j < HID) {
            const float* gp = gi + (long)(t * BB + b) * 768;
            float r = 1.0f / (1.0f + __expf(-(gp[j]       + g_s[j])));
            float z = 1.0f / (1.0f + __expf(-(gp[j + 256] + g_s[j + 256])));
            float npre = gp[j + 512] + r * g_s[j + 512];
            float n = 2.0f / (1.0f + __expf(-2.0f * npre)) - 1.0f;  // tanh
            h_s[j] = (1.0f - z) * n + z * h_s[j];
        }
        __syncthreads();                         // h ready for next step
    }
    if (j < OUTN) {
        float acc = isf32 ? ((const float*)bout)[j] : bf16s(((const uint16_t*)bout)[j]);
        if (!isf32) {
            const uint4* wo = reinterpret_cast<const uint4*>((const uint16_t*)Wout + (long)j * HID);
            #pragma unroll
            for (int k = 0; k < 32; k++) {
                uint4 v = wo[k];
                const float* hp2 = &h_s[k * 8];
                acc += bf16lo(v.x) * hp2[0] + bf16hi(v.x) * hp2[1]
                     + bf16lo(v.y) * hp2[2] + bf16hi(v.y) * hp2[3]
                     + bf16lo(v.z) * hp2[4] + bf16hi(v.z) * hp2[5]
                     + bf16lo(v.w) * hp2[6] + bf16hi(v.w) * hp2[7];
            }
            ((uint16_t*)out)[b * OUTN + j] = f32_to_bf16_rne(acc);
        } else {
            const float4* wo = reinterpret_cast<const float4*>((const float*)Wout + (long)j * HID);
            #pragma unroll
            for (int k = 0; k < 64; k++) {
                float4 v = wo[k];
                const float* hp2 = &h_s[k * 4];
                acc += v.x * hp2[0] + v.y * hp2[1] + v.z * hp2[2] + v.w * hp2[3];
            }
            ((float*)out)[b * OUTN + j] = acc;
        }
    }
}

extern "C" void kernel_launch(void* const* d_in, const int* in_sizes, int n_in,
                              void* d_out, int out_size, void* d_ws, size_t ws_size,
                              hipStream_t stream) {
    const void* x    = d_in[0];  // 8*16*32*112*112
    const void* Wih  = d_in[1];  // 768*784
    const void* Whh  = d_in[2];  // 768*256
    const void* bih  = d_in[3];  // 768
    const void* bhh  = d_in[4];  // 768
    const void* Wout = d_in[5];  // 128*256
    const void* bout = d_in[6];  // 128

    char* ws = (char*)d_ws;
    float*    seq  = (float*)ws;                  // 401408 B
    float*    gi   = (float*)(ws + 401408);       // 393216 B
    float*    wihT = (float*)(ws + 1048576);      // 2408448 B  [784][768] f32
    uint32_t* whhP = (uint32_t*)(ws + 4194304);   // 393216 B   [128][768] u32
    int*     flagp = (int*)(ws + 8388608);

    detect_kernel<<<1, 256, 0, stream>>>((const uint16_t*)x, flagp);
    pool_kernel<<<2048, 256, 0, stream>>>(x, seq, flagp);
    pack_all<<<924, 256, 0, stream>>>(Wih, wihT, Whh, whhP, bih, gi, flagp);
    gi_kernel<<<192, 256, 0, stream>>>(seq, wihT, gi);
    gru_kernel<<<8, 768, 0, stream>>>(gi, whhP, bhh, Wout, bout, d_out, flagp);
}